// Round 4
// baseline (222.313 us; speedup 1.0000x reference)
//
#include <hip/hip_runtime.h>

#define N_NODESC 50000
#define N_EDGESC 800000
#define MAXDEG 64

typedef short bf16x8 __attribute__((ext_vector_type(8)));   // 8 bf16 = 4 VGPRs
typedef short short4v __attribute__((ext_vector_type(4)));  // 8B LDS store
typedef float f32x4  __attribute__((ext_vector_type(4)));

__device__ inline unsigned short f2bf(float f) {            // RNE fp32->bf16
    unsigned u = __float_as_uint(f);
    unsigned r = u + 0x7FFFu + ((u >> 16) & 1u);
    return (unsigned short)(r >> 16);
}
__device__ inline float bf2f(unsigned short h) {
    return __uint_as_float(((unsigned)h) << 16);
}

// ---------------- KW0: init (deg, z) + one-time W prepack -------------------
// 196 blocks zero deg/z; blocks 0-3 additionally pack W1r|W1l into bf16
// hi/lo MFMA-fragment order pk[ks][quad][o][j] so k3's B-frag loads are
// coalesced dwordx4 runs. Element (o,ks,quad,j) = W_cat[o][ks*32+quad*8+j]
// (k<64: W1r, else W1l) -- identical values to on-the-fly conversion.
__global__ void kW0_init_pack(const float* __restrict__ W1l, const float* __restrict__ W1r,
                              short* __restrict__ pkhi, short* __restrict__ pklo,
                              int* __restrict__ deg, float* __restrict__ z) {
    int i = blockIdx.x * 256 + threadIdx.x;
    if (i < N_NODESC) deg[i] = 0;
    if (i < 256) z[i] = 0.0f;
    if (blockIdx.x < 4) {
        int ks = blockIdx.x;            // 0..3
        int t  = threadIdx.x;           // 256
        int o  = t & 127;
        int h  = t >> 7;                // quads {2h, 2h+1}
        const float* src = (ks < 2) ? (W1r + o * 64 + ks * 32)
                                    : (W1l + o * 64 + (ks - 2) * 32);
        #pragma unroll
        for (int qi = 0; qi < 2; qi++) {
            int q = 2 * h + qi;
            float4 a = *(const float4*)(src + q * 8);
            float4 b = *(const float4*)(src + q * 8 + 4);
            float v[8] = {a.x, a.y, a.z, a.w, b.x, b.y, b.z, b.w};
            bf16x8 hv, lv;
            #pragma unroll
            for (int j = 0; j < 8; j++) {
                unsigned short hh = f2bf(v[j]);
                hv[j] = (short)hh;
                lv[j] = (short)f2bf(v[j] - bf2f(hh));
            }
            int idx = ((ks * 4 + q) * 128 + o) * 8;
            *(bf16x8*)&pkhi[idx] = hv;
            *(bf16x8*)&pklo[idx] = lv;
        }
    }
}

// ---------------- K1: XCD-partitioned padded-bucket CSR build ---------------
#define K1_BLOCKS 2048
#define K1_EPB (N_EDGESC / (K1_BLOCKS / 8))   // 3125 edges per block
__global__ void k1_bucket(const int* __restrict__ ei, int* __restrict__ deg,
                          int* __restrict__ bucket) {
    int g   = blockIdx.x & 7;
    int idx = blockIdx.x >> 3;
    int lo = g * (N_NODESC / 8), hi = lo + (N_NODESC / 8);
    int e0 = idx * K1_EPB;
    for (int i = threadIdx.x; i < K1_EPB; i += 256) {
        int e = e0 + i;
        int dst = ei[N_EDGESC + e];
        int src = ei[e];
        if (dst >= lo && dst < hi) {
            int slot = atomicAdd(&deg[dst], 1);
            if (slot < MAXDEG) bucket[dst * MAXDEG + slot] = src;
        }
    }
}

// ---------------- K3: fused gather-mean + 3-term bf16 MFMA + epilogue -------
// v5: 32-node tile (was 64). Round-3 counters showed the fused gather is
// latency-bound (Occ 28%, VALU 20%, HBM 21%): 12 waves/CU can't cover the
// ~300-500cyc L2/L3 gather latency. Halving the tile halves LDS (38.9->19.5
// KB) and doubles resident blocks (launch_bounds 6 -> 24 waves/CU), doubling
// outstanding gathers; MFMA per-block efficiency halves but MfmaUtil was
// 3.5% -- irrelevant. Gather keeps k2's exact per-node FP accumulate order
// (bit-identical), two interleaved node-chains per wave, 4 pairs per wave.
// 16x16x32 layouts (m89/m120): A[m=lane&15][k=quad*8+j],
// B[k=quad*8+j][n=lane&15], D[m=quad*4+reg][n=lane&15].
#define K3S 144   // LDS row stride in bf16 elems (128 + 16 pad)
#define K3BLK 32  // nodes per block

__launch_bounds__(256, 6)
__global__ void k3_fused(const float* __restrict__ x,
                         const int* __restrict__ deg, const int* __restrict__ bucket,
                         const short* __restrict__ pkhi, const short* __restrict__ pklo,
                         const float* __restrict__ b1l,
                         const float* __restrict__ W2l, const float* __restrict__ W2r,
                         float* __restrict__ s_out, float* __restrict__ t_out) {
    __shared__ __align__(16) short sAhi[K3BLK * K3S];   // 9216 B
    __shared__ __align__(16) short sAlo[K3BLK * K3S];   // 9216 B
    __shared__ float sSp[4][K3BLK], sTp[4][K3BLK];      // 1024 B

    int tid = threadIdx.x;
    int lane = tid & 63;
    int wave = tid >> 6;
    int col = lane & 15;   // c4 for gather, n-col for MFMA
    int quad = lane >> 4;  // g for gather, k-quad for MFMA
    int node0 = blockIdx.x * K3BLK;

    // ---- issue x-half staging loads first (cols 0..63): 1 chunk/thread -----
    float4 sv0, sv1;
    {
        int n = tid >> 3, kc = tid & 7;   // 32 rows x 8 chunks
        int node = node0 + n;
        if (node < N_NODESC) {
            const float* src = x + node * 64 + kc * 8;
            sv0 = *(const float4*)src;
            sv1 = *(const float4*)(src + 4);
        } else {
            sv0 = make_float4(0.f, 0.f, 0.f, 0.f);
            sv1 = make_float4(0.f, 0.f, 0.f, 0.f);
        }
    }

    // ---- convert staged x rows to bf16 hi/lo, write LDS cols 0..63 ---------
    {
        int n = tid >> 3, kc = tid & 7;
        float v[8] = {sv0.x, sv0.y, sv0.z, sv0.w, sv1.x, sv1.y, sv1.z, sv1.w};
        bf16x8 hv, lv;
        #pragma unroll
        for (int j = 0; j < 8; j++) {
            unsigned short h = f2bf(v[j]);
            hv[j] = (short)h;
            lv[j] = (short)f2bf(v[j] - bf2f(h));
        }
        *(bf16x8*)&sAhi[n * K3S + kc * 8] = hv;
        *(bf16x8*)&sAlo[n * K3S + kc * 8] = lv;
    }

    // ---- gather-mean agg half (cols 64..127): 4 node-PAIRS per wave --------
    {
        int base = node0 + wave * 8;
        int dA = 0, bA = 0, dB = 0, bB = 0;
        if (base < N_NODESC)     { dA = deg[base];     bA = bucket[base * MAXDEG + lane]; }
        if (base + 1 < N_NODESC) { dB = deg[base + 1]; bB = bucket[(base + 1) * MAXDEG + lane]; }
        for (int np = 0; np < 4; np++) {
            // prefetch next pair's deg + bucket rows (overlaps current gathers)
            int nN = base + 2 * np + 2;
            int dA2 = 0, bA2 = 0, dB2 = 0, bB2 = 0;
            if (np < 3) {
                if (nN < N_NODESC)     { dA2 = deg[nN];     bA2 = bucket[nN * MAXDEG + lane]; }
                if (nN + 1 < N_NODESC) { dB2 = deg[nN + 1]; bB2 = bucket[(nN + 1) * MAXDEG + lane]; }
            }
            int cA = min(dA, MAXDEG);
            int cB = min(dB, MAXDEG);
            int kmax = max(cA, cB);
            float4 aA = make_float4(0.f, 0.f, 0.f, 0.f);
            float4 aB = make_float4(0.f, 0.f, 0.f, 0.f);
            for (int k = 0; k < kmax; k += 8) {
                int i0 = k + quad, i1 = k + 4 + quad;
                int a0 = __shfl(bA, i0);
                int a1 = __shfl(bA, i1);
                int b0 = __shfl(bB, i0);
                int b1 = __shfl(bB, i1);
                if (i0 < cA) {
                    float4 v = ((const float4*)(x + a0 * 64))[col];
                    aA.x += v.x; aA.y += v.y; aA.z += v.z; aA.w += v.w;
                }
                if (i1 < cA) {
                    float4 v = ((const float4*)(x + a1 * 64))[col];
                    aA.x += v.x; aA.y += v.y; aA.z += v.z; aA.w += v.w;
                }
                if (i0 < cB) {
                    float4 v = ((const float4*)(x + b0 * 64))[col];
                    aB.x += v.x; aB.y += v.y; aB.z += v.z; aB.w += v.w;
                }
                if (i1 < cB) {
                    float4 v = ((const float4*)(x + b1 * 64))[col];
                    aB.x += v.x; aB.y += v.y; aB.z += v.z; aB.w += v.w;
                }
            }
            #pragma unroll
            for (int m = 16; m <= 32; m <<= 1) {
                aA.x += __shfl_xor(aA.x, m);
                aA.y += __shfl_xor(aA.y, m);
                aA.z += __shfl_xor(aA.z, m);
                aA.w += __shfl_xor(aA.w, m);
                aB.x += __shfl_xor(aB.x, m);
                aB.y += __shfl_xor(aB.y, m);
                aB.z += __shfl_xor(aB.z, m);
                aB.w += __shfl_xor(aB.w, m);
            }
            if (quad == 0) {
                int nlocA = wave * 8 + 2 * np;
                float invA = 1.0f / (float)max(dA, 1);
                float invB = 1.0f / (float)max(dB, 1);
                float vA[4] = {aA.x * invA, aA.y * invA, aA.z * invA, aA.w * invA};
                float vB[4] = {aB.x * invB, aB.y * invB, aB.z * invB, aB.w * invB};
                short4v hvA, lvA, hvB, lvB;
                #pragma unroll
                for (int j = 0; j < 4; j++) {
                    unsigned short hA = f2bf(vA[j]);
                    hvA[j] = (short)hA;
                    lvA[j] = (short)f2bf(vA[j] - bf2f(hA));
                    unsigned short hB = f2bf(vB[j]);
                    hvB[j] = (short)hB;
                    lvB[j] = (short)f2bf(vB[j] - bf2f(hB));
                }
                *(short4v*)&sAhi[nlocA * K3S + 64 + col * 4] = hvA;
                *(short4v*)&sAlo[nlocA * K3S + 64 + col * 4] = lvA;
                *(short4v*)&sAhi[(nlocA + 1) * K3S + 64 + col * 4] = hvB;
                *(short4v*)&sAlo[(nlocA + 1) * K3S + 64 + col * 4] = lvB;
            }
            dA = dA2; bA = bA2; dB = dB2; bB = bB2;
        }
    }

    // ---- B fragments: coalesced vector loads of prepacked hi/lo ------------
    // (after gather: keeps 64+ VGPRs dead during the latency-critical phase;
    //  pk* is 64KB L2-resident so this load is ~200cyc, hidden by the barrier)
    int o_base = wave * 32;
    bf16x8 bhi[2][4], blo[2][4];
    float bias_r[2], w2l_r[2], w2r_r[2];
    #pragma unroll
    for (int oc = 0; oc < 2; oc++) {
        int o = o_base + oc * 16 + col;
        bias_r[oc] = b1l[o]; w2l_r[oc] = W2l[o]; w2r_r[oc] = W2r[o];
        #pragma unroll
        for (int ks = 0; ks < 4; ks++) {
            int idx = ((ks * 4 + quad) * 128 + o) * 8;
            bhi[oc][ks] = *(const bf16x8*)&pkhi[idx];
            blo[oc][ks] = *(const bf16x8*)&pklo[idx];
        }
    }
    __syncthreads();

    // ---- main loop: 4 ksteps x 2 node-tiles x 2 out-tiles x 3 terms --------
    f32x4 acc[2][2];
    #pragma unroll
    for (int nt = 0; nt < 2; nt++)
        #pragma unroll
        for (int oc = 0; oc < 2; oc++) acc[nt][oc] = (f32x4)0.f;

    #pragma unroll
    for (int ks = 0; ks < 4; ks++) {
        #pragma unroll
        for (int nt = 0; nt < 2; nt++) {
            int off = (nt * 16 + col) * K3S + ks * 32 + quad * 8;
            bf16x8 ah = *(const bf16x8*)&sAhi[off];
            bf16x8 al = *(const bf16x8*)&sAlo[off];
            #pragma unroll
            for (int oc = 0; oc < 2; oc++) {
                acc[nt][oc] = __builtin_amdgcn_mfma_f32_16x16x32_bf16(ah, bhi[oc][ks], acc[nt][oc], 0, 0, 0);
                acc[nt][oc] = __builtin_amdgcn_mfma_f32_16x16x32_bf16(al, bhi[oc][ks], acc[nt][oc], 0, 0, 0);
                acc[nt][oc] = __builtin_amdgcn_mfma_f32_16x16x32_bf16(ah, blo[oc][ks], acc[nt][oc], 0, 0, 0);
            }
        }
    }

    // ---- epilogue: bias+relu+dots; col-lane shfl reduce + per-wave partials -
    #pragma unroll
    for (int nt = 0; nt < 2; nt++) {
        float sp[4] = {0.f, 0.f, 0.f, 0.f};
        float tp[4] = {0.f, 0.f, 0.f, 0.f};
        #pragma unroll
        for (int oc = 0; oc < 2; oc++)
            #pragma unroll
            for (int reg = 0; reg < 4; reg++) {
                float h = fmaxf(acc[nt][oc][reg] + bias_r[oc], 0.f);
                sp[reg] += h * w2l_r[oc];
                tp[reg] += h * w2r_r[oc];
            }
        #pragma unroll
        for (int reg = 0; reg < 4; reg++) {
            #pragma unroll
            for (int m = 1; m <= 8; m <<= 1) {
                sp[reg] += __shfl_xor(sp[reg], m);
                tp[reg] += __shfl_xor(tp[reg], m);
            }
        }
        if (col == 0) {
            int nn = nt * 16 + quad * 4;
            #pragma unroll
            for (int reg = 0; reg < 4; reg++) {
                sSp[wave][nn + reg] = sp[reg];
                sTp[wave][nn + reg] = tp[reg];
            }
        }
    }
    __syncthreads();
    if (tid < K3BLK) {
        int node = node0 + tid;
        if (node < N_NODESC) {
            s_out[node] = sSp[0][tid] + sSp[1][tid] + sSp[2][tid] + sSp[3][tid];
            t_out[node] = sTp[0][tid] + sTp[1][tid] + sTp[2][tid] + sTp[3][tid];
        }
    }
}

// ---------------- K4: layer-2 scalar aggregation + relu -> v ----------------
__global__ void k4_layer2(const float* __restrict__ s, const float* __restrict__ t,
                          const int* __restrict__ deg, const int* __restrict__ bucket,
                          const float* __restrict__ b2l, float* __restrict__ v) {
    int tid = threadIdx.x;
    int lane = tid & 15;
    int node = blockIdx.x * 16 + (tid >> 4);
    int d = deg[node];
    int c = min(d, MAXDEG);
    float sum = 0.f;
    for (int k = lane; k < c; k += 16) sum += s[bucket[node * MAXDEG + k]];
    sum += __shfl_xor(sum, 1);
    sum += __shfl_xor(sum, 2);
    sum += __shfl_xor(sum, 4);
    sum += __shfl_xor(sum, 8);
    if (lane == 0) {
        float h = sum / (float)max(d, 1) + b2l[0] + t[node];
        v[node] = fmaxf(h, 0.f);
    }
}

// ---------------- K5: z_partial = fc1_W @ v (bias deferred to K6) -----------
// (reverted round-2's fused head: its per-block __threadfence() forced
//  device-scope L2 ordering across XCDs, 10us -> 102us. Separate k6 is cheap.)
__global__ void k5_fc1(const float* __restrict__ fc1W, const float* __restrict__ v,
                       float* __restrict__ z) {
    int row = blockIdx.x >> 2;
    int part = blockIdx.x & 3;
    const float4* W4 = (const float4*)(fc1W + row * 50000 + part * 12500);
    const float4* v4 = (const float4*)(v + part * 12500);
    float sum = 0.f;
    for (int i = threadIdx.x; i < 3125; i += 256) {
        float4 w = W4[i], a = v4[i];
        sum += w.x * a.x + w.y * a.y + w.z * a.z + w.w * a.w;
    }
    #pragma unroll
    for (int m = 1; m < 64; m <<= 1) sum += __shfl_xor(sum, m);
    __shared__ float red[4];
    if ((threadIdx.x & 63) == 0) red[threadIdx.x >> 6] = sum;
    __syncthreads();
    if (threadIdx.x == 0) atomicAdd(&z[row], red[0] + red[1] + red[2] + red[3]);
}

// ---------------- K6: pred = fc2_W @ (z + fc1_b) + fc2_b --------------------
__global__ void k6_head(const float* __restrict__ z, const float* __restrict__ fc1b,
                        const float* __restrict__ fc2W, const float* __restrict__ fc2b,
                        float* __restrict__ out) {
    int t = threadIdx.x;  // 256 threads
    float val = (z[t] + fc1b[t]) * fc2W[t];
    #pragma unroll
    for (int m = 1; m < 64; m <<= 1) val += __shfl_xor(val, m);
    __shared__ float red[4];
    if ((t & 63) == 0) red[t >> 6] = val;
    __syncthreads();
    if (t == 0) out[0] = red[0] + red[1] + red[2] + red[3] + fc2b[0];
}

extern "C" void kernel_launch(void* const* d_in, const int* in_sizes, int n_in,
                              void* d_out, int out_size, void* d_ws, size_t ws_size,
                              hipStream_t stream) {
    const float* x    = (const float*)d_in[0];
    const int*   ei   = (const int*)d_in[1];   // jax x64 disabled -> int32
    const float* W1l  = (const float*)d_in[2];
    const float* b1l  = (const float*)d_in[3];
    const float* W1r  = (const float*)d_in[4];
    const float* W2l  = (const float*)d_in[5];
    const float* b2l  = (const float*)d_in[6];
    const float* W2r  = (const float*)d_in[7];
    const float* fc1W = (const float*)d_in[8];
    const float* fc1b = (const float*)d_in[9];
    const float* fc2W = (const float*)d_in[10];
    const float* fc2b = (const float*)d_in[11];
    float* out = (float*)d_out;

    // workspace layout (bytes, 512-aligned)
    char* ws = (char*)d_ws;
    int*   deg    = (int*)  (ws + 0);          //   200,000 B
    float* z      = (float*)(ws + 200192);     //     1,024 B
    int*   bucket = (int*)  (ws + 201216);     // 12,800,000 B
    float* s      = (float*)(ws + 13001216);   //   200,000 B
    float* t      = (float*)(ws + 13201216);   //   200,000 B
    float* v      = (float*)(ws + 13401216);   //   200,000 B
    short* pkhi   = (short*)(ws + 13601280);   //    32,768 B (prepacked W hi)
    short* pklo   = (short*)(ws + 13634048);   //    32,768 B (prepacked W lo)
                                               // end 13,666,816

    kW0_init_pack<<<196,  256, 0, stream>>>(W1l, W1r, pkhi, pklo, deg, z);
    k1_bucket    <<<K1_BLOCKS, 256, 0, stream>>>(ei, deg, bucket);
    k3_fused     <<<1563, 256, 0, stream>>>(x, deg, bucket, pkhi, pklo, b1l, W2l, W2r, s, t);
    k4_layer2    <<<3125, 256, 0, stream>>>(s, t, deg, bucket, b2l, v);
    k5_fc1       <<<1024, 256, 0, stream>>>(fc1W, v, z);
    k6_head      <<<1,    256, 0, stream>>>(z, fc1b, fc2W, fc2b, out);
}

// Round 5
// 207.542 us; speedup vs baseline: 1.0712x; 1.0712x over previous
//
#include <hip/hip_runtime.h>

#define N_NODESC 50000
#define N_EDGESC 800000
#define MAXDEG 64

typedef short bf16x8 __attribute__((ext_vector_type(8)));   // 8 bf16 = 4 VGPRs
typedef short short4v __attribute__((ext_vector_type(4)));  // 8B LDS store
typedef float f32x4  __attribute__((ext_vector_type(4)));

__device__ inline unsigned short f2bf(float f) {            // RNE fp32->bf16
    unsigned u = __float_as_uint(f);
    unsigned r = u + 0x7FFFu + ((u >> 16) & 1u);
    return (unsigned short)(r >> 16);
}
__device__ inline float bf2f(unsigned short h) {
    return __uint_as_float(((unsigned)h) << 16);
}

// ---------------- KW0: init (deg, z) + one-time W prepack -------------------
// 196 blocks zero deg/z; blocks 0-3 additionally pack W1r|W1l into bf16
// hi/lo MFMA-fragment order pk[ks][quad][o][j] so k3's B-frag loads are
// coalesced dwordx4 runs. Element (o,ks,quad,j) = W_cat[o][ks*32+quad*8+j]
// (k<64: W1r, else W1l) -- identical values to on-the-fly conversion.
__global__ void kW0_init_pack(const float* __restrict__ W1l, const float* __restrict__ W1r,
                              short* __restrict__ pkhi, short* __restrict__ pklo,
                              int* __restrict__ deg, float* __restrict__ z) {
    int i = blockIdx.x * 256 + threadIdx.x;
    if (i < N_NODESC) deg[i] = 0;
    if (i < 256) z[i] = 0.0f;
    if (blockIdx.x < 4) {
        int ks = blockIdx.x;            // 0..3
        int t  = threadIdx.x;           // 256
        int o  = t & 127;
        int h  = t >> 7;                // quads {2h, 2h+1}
        const float* src = (ks < 2) ? (W1r + o * 64 + ks * 32)
                                    : (W1l + o * 64 + (ks - 2) * 32);
        #pragma unroll
        for (int qi = 0; qi < 2; qi++) {
            int q = 2 * h + qi;
            float4 a = *(const float4*)(src + q * 8);
            float4 b = *(const float4*)(src + q * 8 + 4);
            float v[8] = {a.x, a.y, a.z, a.w, b.x, b.y, b.z, b.w};
            bf16x8 hv, lv;
            #pragma unroll
            for (int j = 0; j < 8; j++) {
                unsigned short hh = f2bf(v[j]);
                hv[j] = (short)hh;
                lv[j] = (short)f2bf(v[j] - bf2f(hh));
            }
            int idx = ((ks * 4 + q) * 128 + o) * 8;
            *(bf16x8*)&pkhi[idx] = hv;
            *(bf16x8*)&pklo[idx] = lv;
        }
    }
}

// ---------------- K1: XCD-partitioned padded-bucket CSR build ---------------
// v6: 4 dst-range groups (was 8). The 8-group variant re-reads the 6.4 MB
// edge list 8x (6.4M edge visits); 4 groups halves that to 3.2M while each
// group's bucket slice (12500 nodes * 256 B = 3.2 MB) still fits one XCD L2.
// 800000/512 blocks doesn't divide -> per-edge guard.
#define K1_BLOCKS 2048
#define K1_EPB 1563   // ceil(800000 / 512)
__global__ void k1_bucket(const int* __restrict__ ei, int* __restrict__ deg,
                          int* __restrict__ bucket) {
    int g   = blockIdx.x & 3;
    int idx = blockIdx.x >> 2;
    int lo = g * (N_NODESC / 4), hi = lo + (N_NODESC / 4);
    int e0 = idx * K1_EPB;
    for (int i = threadIdx.x; i < K1_EPB; i += 256) {
        int e = e0 + i;
        if (e < N_EDGESC) {
            int dst = ei[N_EDGESC + e];
            int src = ei[e];
            if (dst >= lo && dst < hi) {
                int slot = atomicAdd(&deg[dst], 1);
                if (slot < MAXDEG) bucket[dst * MAXDEG + slot] = src;
            }
        }
    }
}

// ---------------- K3: fused gather-mean + 3-term bf16 MFMA + epilogue -------
// v6: 32-node tile, launch_bounds(256,3). Round-4's (256,6) capped regs at
// ~85 < live set (64 B-frag VGPRs + acc) -> scratch spill (WRITE_SIZE 30 MB,
// VGPR 40, +15us). Bound 3 restores the round-3 no-spill regalloc (cap ~170)
// while keeping the 1563-block grid (6.1 blocks/CU available vs round-3's
// 3.05 -- the real occupancy limiter was grid size, not LDS). LDS 19.5 KB
// allows 8 blocks/CU; regs ~4 -> expect ~16 waves/CU for the latency-bound
// gather. Gather keeps k2's exact per-node FP accumulate order.
// 16x16x32 layouts (m89/m120): A[m=lane&15][k=quad*8+j],
// B[k=quad*8+j][n=lane&15], D[m=quad*4+reg][n=lane&15].
#define K3S 144   // LDS row stride in bf16 elems (128 + 16 pad)
#define K3BLK 32  // nodes per block

__launch_bounds__(256, 3)
__global__ void k3_fused(const float* __restrict__ x,
                         const int* __restrict__ deg, const int* __restrict__ bucket,
                         const short* __restrict__ pkhi, const short* __restrict__ pklo,
                         const float* __restrict__ b1l,
                         const float* __restrict__ W2l, const float* __restrict__ W2r,
                         float* __restrict__ s_out, float* __restrict__ t_out) {
    __shared__ __align__(16) short sAhi[K3BLK * K3S];   // 9216 B
    __shared__ __align__(16) short sAlo[K3BLK * K3S];   // 9216 B
    __shared__ float sSp[4][K3BLK], sTp[4][K3BLK];      // 1024 B

    int tid = threadIdx.x;
    int lane = tid & 63;
    int wave = tid >> 6;
    int col = lane & 15;   // c4 for gather, n-col for MFMA
    int quad = lane >> 4;  // g for gather, k-quad for MFMA
    int node0 = blockIdx.x * K3BLK;

    // ---- issue x-half staging loads first (cols 0..63): 1 chunk/thread -----
    float4 sv0, sv1;
    {
        int n = tid >> 3, kc = tid & 7;   // 32 rows x 8 chunks
        int node = node0 + n;
        if (node < N_NODESC) {
            const float* src = x + node * 64 + kc * 8;
            sv0 = *(const float4*)src;
            sv1 = *(const float4*)(src + 4);
        } else {
            sv0 = make_float4(0.f, 0.f, 0.f, 0.f);
            sv1 = make_float4(0.f, 0.f, 0.f, 0.f);
        }
    }

    // ---- convert staged x rows to bf16 hi/lo, write LDS cols 0..63 ---------
    {
        int n = tid >> 3, kc = tid & 7;
        float v[8] = {sv0.x, sv0.y, sv0.z, sv0.w, sv1.x, sv1.y, sv1.z, sv1.w};
        bf16x8 hv, lv;
        #pragma unroll
        for (int j = 0; j < 8; j++) {
            unsigned short h = f2bf(v[j]);
            hv[j] = (short)h;
            lv[j] = (short)f2bf(v[j] - bf2f(h));
        }
        *(bf16x8*)&sAhi[n * K3S + kc * 8] = hv;
        *(bf16x8*)&sAlo[n * K3S + kc * 8] = lv;
    }

    // ---- gather-mean agg half (cols 64..127): 4 node-PAIRS per wave --------
    {
        int base = node0 + wave * 8;
        int dA = 0, bA = 0, dB = 0, bB = 0;
        if (base < N_NODESC)     { dA = deg[base];     bA = bucket[base * MAXDEG + lane]; }
        if (base + 1 < N_NODESC) { dB = deg[base + 1]; bB = bucket[(base + 1) * MAXDEG + lane]; }
        for (int np = 0; np < 4; np++) {
            // prefetch next pair's deg + bucket rows (overlaps current gathers)
            int nN = base + 2 * np + 2;
            int dA2 = 0, bA2 = 0, dB2 = 0, bB2 = 0;
            if (np < 3) {
                if (nN < N_NODESC)     { dA2 = deg[nN];     bA2 = bucket[nN * MAXDEG + lane]; }
                if (nN + 1 < N_NODESC) { dB2 = deg[nN + 1]; bB2 = bucket[(nN + 1) * MAXDEG + lane]; }
            }
            int cA = min(dA, MAXDEG);
            int cB = min(dB, MAXDEG);
            int kmax = max(cA, cB);
            float4 aA = make_float4(0.f, 0.f, 0.f, 0.f);
            float4 aB = make_float4(0.f, 0.f, 0.f, 0.f);
            for (int k = 0; k < kmax; k += 8) {
                int i0 = k + quad, i1 = k + 4 + quad;
                int a0 = __shfl(bA, i0);
                int a1 = __shfl(bA, i1);
                int b0 = __shfl(bB, i0);
                int b1 = __shfl(bB, i1);
                if (i0 < cA) {
                    float4 v = ((const float4*)(x + a0 * 64))[col];
                    aA.x += v.x; aA.y += v.y; aA.z += v.z; aA.w += v.w;
                }
                if (i1 < cA) {
                    float4 v = ((const float4*)(x + a1 * 64))[col];
                    aA.x += v.x; aA.y += v.y; aA.z += v.z; aA.w += v.w;
                }
                if (i0 < cB) {
                    float4 v = ((const float4*)(x + b0 * 64))[col];
                    aB.x += v.x; aB.y += v.y; aB.z += v.z; aB.w += v.w;
                }
                if (i1 < cB) {
                    float4 v = ((const float4*)(x + b1 * 64))[col];
                    aB.x += v.x; aB.y += v.y; aB.z += v.z; aB.w += v.w;
                }
            }
            #pragma unroll
            for (int m = 16; m <= 32; m <<= 1) {
                aA.x += __shfl_xor(aA.x, m);
                aA.y += __shfl_xor(aA.y, m);
                aA.z += __shfl_xor(aA.z, m);
                aA.w += __shfl_xor(aA.w, m);
                aB.x += __shfl_xor(aB.x, m);
                aB.y += __shfl_xor(aB.y, m);
                aB.z += __shfl_xor(aB.z, m);
                aB.w += __shfl_xor(aB.w, m);
            }
            if (quad == 0) {
                int nlocA = wave * 8 + 2 * np;
                float invA = 1.0f / (float)max(dA, 1);
                float invB = 1.0f / (float)max(dB, 1);
                float vA[4] = {aA.x * invA, aA.y * invA, aA.z * invA, aA.w * invA};
                float vB[4] = {aB.x * invB, aB.y * invB, aB.z * invB, aB.w * invB};
                short4v hvA, lvA, hvB, lvB;
                #pragma unroll
                for (int j = 0; j < 4; j++) {
                    unsigned short hA = f2bf(vA[j]);
                    hvA[j] = (short)hA;
                    lvA[j] = (short)f2bf(vA[j] - bf2f(hA));
                    unsigned short hB = f2bf(vB[j]);
                    hvB[j] = (short)hB;
                    lvB[j] = (short)f2bf(vB[j] - bf2f(hB));
                }
                *(short4v*)&sAhi[nlocA * K3S + 64 + col * 4] = hvA;
                *(short4v*)&sAlo[nlocA * K3S + 64 + col * 4] = lvA;
                *(short4v*)&sAhi[(nlocA + 1) * K3S + 64 + col * 4] = hvB;
                *(short4v*)&sAlo[(nlocA + 1) * K3S + 64 + col * 4] = lvB;
            }
            dA = dA2; bA = bA2; dB = dB2; bB = bB2;
        }
    }

    // ---- B fragments: coalesced vector loads of prepacked hi/lo ------------
    // (after gather: keeps 64+ VGPRs dead during the latency-critical phase;
    //  pk* is 64KB L2-resident so this load is ~200cyc, hidden by the barrier)
    int o_base = wave * 32;
    bf16x8 bhi[2][4], blo[2][4];
    float bias_r[2], w2l_r[2], w2r_r[2];
    #pragma unroll
    for (int oc = 0; oc < 2; oc++) {
        int o = o_base + oc * 16 + col;
        bias_r[oc] = b1l[o]; w2l_r[oc] = W2l[o]; w2r_r[oc] = W2r[o];
        #pragma unroll
        for (int ks = 0; ks < 4; ks++) {
            int idx = ((ks * 4 + quad) * 128 + o) * 8;
            bhi[oc][ks] = *(const bf16x8*)&pkhi[idx];
            blo[oc][ks] = *(const bf16x8*)&pklo[idx];
        }
    }
    __syncthreads();

    // ---- main loop: 4 ksteps x 2 node-tiles x 2 out-tiles x 3 terms --------
    f32x4 acc[2][2];
    #pragma unroll
    for (int nt = 0; nt < 2; nt++)
        #pragma unroll
        for (int oc = 0; oc < 2; oc++) acc[nt][oc] = (f32x4)0.f;

    #pragma unroll
    for (int ks = 0; ks < 4; ks++) {
        #pragma unroll
        for (int nt = 0; nt < 2; nt++) {
            int off = (nt * 16 + col) * K3S + ks * 32 + quad * 8;
            bf16x8 ah = *(const bf16x8*)&sAhi[off];
            bf16x8 al = *(const bf16x8*)&sAlo[off];
            #pragma unroll
            for (int oc = 0; oc < 2; oc++) {
                acc[nt][oc] = __builtin_amdgcn_mfma_f32_16x16x32_bf16(ah, bhi[oc][ks], acc[nt][oc], 0, 0, 0);
                acc[nt][oc] = __builtin_amdgcn_mfma_f32_16x16x32_bf16(al, bhi[oc][ks], acc[nt][oc], 0, 0, 0);
                acc[nt][oc] = __builtin_amdgcn_mfma_f32_16x16x32_bf16(ah, blo[oc][ks], acc[nt][oc], 0, 0, 0);
            }
        }
    }

    // ---- epilogue: bias+relu+dots; col-lane shfl reduce + per-wave partials -
    #pragma unroll
    for (int nt = 0; nt < 2; nt++) {
        float sp[4] = {0.f, 0.f, 0.f, 0.f};
        float tp[4] = {0.f, 0.f, 0.f, 0.f};
        #pragma unroll
        for (int oc = 0; oc < 2; oc++)
            #pragma unroll
            for (int reg = 0; reg < 4; reg++) {
                float h = fmaxf(acc[nt][oc][reg] + bias_r[oc], 0.f);
                sp[reg] += h * w2l_r[oc];
                tp[reg] += h * w2r_r[oc];
            }
        #pragma unroll
        for (int reg = 0; reg < 4; reg++) {
            #pragma unroll
            for (int m = 1; m <= 8; m <<= 1) {
                sp[reg] += __shfl_xor(sp[reg], m);
                tp[reg] += __shfl_xor(tp[reg], m);
            }
        }
        if (col == 0) {
            int nn = nt * 16 + quad * 4;
            #pragma unroll
            for (int reg = 0; reg < 4; reg++) {
                sSp[wave][nn + reg] = sp[reg];
                sTp[wave][nn + reg] = tp[reg];
            }
        }
    }
    __syncthreads();
    if (tid < K3BLK) {
        int node = node0 + tid;
        if (node < N_NODESC) {
            s_out[node] = sSp[0][tid] + sSp[1][tid] + sSp[2][tid] + sSp[3][tid];
            t_out[node] = sTp[0][tid] + sTp[1][tid] + sTp[2][tid] + sTp[3][tid];
        }
    }
}

// ---------------- K4: layer-2 scalar aggregation + relu -> v ----------------
__global__ void k4_layer2(const float* __restrict__ s, const float* __restrict__ t,
                          const int* __restrict__ deg, const int* __restrict__ bucket,
                          const float* __restrict__ b2l, float* __restrict__ v) {
    int tid = threadIdx.x;
    int lane = tid & 15;
    int node = blockIdx.x * 16 + (tid >> 4);
    int d = deg[node];
    int c = min(d, MAXDEG);
    float sum = 0.f;
    for (int k = lane; k < c; k += 16) sum += s[bucket[node * MAXDEG + k]];
    sum += __shfl_xor(sum, 1);
    sum += __shfl_xor(sum, 2);
    sum += __shfl_xor(sum, 4);
    sum += __shfl_xor(sum, 8);
    if (lane == 0) {
        float h = sum / (float)max(d, 1) + b2l[0] + t[node];
        v[node] = fmaxf(h, 0.f);
    }
}

// ---------------- K5: z_partial = fc1_W @ v (bias deferred to K6) -----------
// (reverted round-2's fused head: its per-block __threadfence() forced
//  device-scope L2 ordering across XCDs, 10us -> 102us. Separate k6 is cheap.)
__global__ void k5_fc1(const float* __restrict__ fc1W, const float* __restrict__ v,
                       float* __restrict__ z) {
    int row = blockIdx.x >> 2;
    int part = blockIdx.x & 3;
    const float4* W4 = (const float4*)(fc1W + row * 50000 + part * 12500);
    const float4* v4 = (const float4*)(v + part * 12500);
    float sum = 0.f;
    for (int i = threadIdx.x; i < 3125; i += 256) {
        float4 w = W4[i], a = v4[i];
        sum += w.x * a.x + w.y * a.y + w.z * a.z + w.w * a.w;
    }
    #pragma unroll
    for (int m = 1; m < 64; m <<= 1) sum += __shfl_xor(sum, m);
    __shared__ float red[4];
    if ((threadIdx.x & 63) == 0) red[threadIdx.x >> 6] = sum;
    __syncthreads();
    if (threadIdx.x == 0) atomicAdd(&z[row], red[0] + red[1] + red[2] + red[3]);
}

// ---------------- K6: pred = fc2_W @ (z + fc1_b) + fc2_b --------------------
__global__ void k6_head(const float* __restrict__ z, const float* __restrict__ fc1b,
                        const float* __restrict__ fc2W, const float* __restrict__ fc2b,
                        float* __restrict__ out) {
    int t = threadIdx.x;  // 256 threads
    float val = (z[t] + fc1b[t]) * fc2W[t];
    #pragma unroll
    for (int m = 1; m < 64; m <<= 1) val += __shfl_xor(val, m);
    __shared__ float red[4];
    if ((t & 63) == 0) red[t >> 6] = val;
    __syncthreads();
    if (t == 0) out[0] = red[0] + red[1] + red[2] + red[3] + fc2b[0];
}

extern "C" void kernel_launch(void* const* d_in, const int* in_sizes, int n_in,
                              void* d_out, int out_size, void* d_ws, size_t ws_size,
                              hipStream_t stream) {
    const float* x    = (const float*)d_in[0];
    const int*   ei   = (const int*)d_in[1];   // jax x64 disabled -> int32
    const float* W1l  = (const float*)d_in[2];
    const float* b1l  = (const float*)d_in[3];
    const float* W1r  = (const float*)d_in[4];
    const float* W2l  = (const float*)d_in[5];
    const float* b2l  = (const float*)d_in[6];
    const float* W2r  = (const float*)d_in[7];
    const float* fc1W = (const float*)d_in[8];
    const float* fc1b = (const float*)d_in[9];
    const float* fc2W = (const float*)d_in[10];
    const float* fc2b = (const float*)d_in[11];
    float* out = (float*)d_out;

    // workspace layout (bytes, 512-aligned)
    char* ws = (char*)d_ws;
    int*   deg    = (int*)  (ws + 0);          //   200,000 B
    float* z      = (float*)(ws + 200192);     //     1,024 B
    int*   bucket = (int*)  (ws + 201216);     // 12,800,000 B
    float* s      = (float*)(ws + 13001216);   //   200,000 B
    float* t      = (float*)(ws + 13201216);   //   200,000 B
    float* v      = (float*)(ws + 13401216);   //   200,000 B
    short* pkhi   = (short*)(ws + 13601280);   //    32,768 B (prepacked W hi)
    short* pklo   = (short*)(ws + 13634048);   //    32,768 B (prepacked W lo)
                                               // end 13,666,816

    kW0_init_pack<<<196,  256, 0, stream>>>(W1l, W1r, pkhi, pklo, deg, z);
    k1_bucket    <<<K1_BLOCKS, 256, 0, stream>>>(ei, deg, bucket);
    k3_fused     <<<1563, 256, 0, stream>>>(x, deg, bucket, pkhi, pklo, b1l, W2l, W2r, s, t);
    k4_layer2    <<<3125, 256, 0, stream>>>(s, t, deg, bucket, b2l, v);
    k5_fc1       <<<1024, 256, 0, stream>>>(fc1W, v, z);
    k6_head      <<<1,    256, 0, stream>>>(z, fc1b, fc2W, fc2b, out);
}

// Round 6
// 201.919 us; speedup vs baseline: 1.1010x; 1.0278x over previous
//
#include <hip/hip_runtime.h>

#define N_NODESC 50000
#define N_EDGESC 800000
#define MAXDEG 64

typedef short bf16x8 __attribute__((ext_vector_type(8)));   // 8 bf16 = 4 VGPRs
typedef short short4v __attribute__((ext_vector_type(4)));  // 8B LDS store
typedef float f32x4  __attribute__((ext_vector_type(4)));

__device__ inline unsigned short f2bf(float f) {            // RNE fp32->bf16
    unsigned u = __float_as_uint(f);
    unsigned r = u + 0x7FFFu + ((u >> 16) & 1u);
    return (unsigned short)(r >> 16);
}
__device__ inline float bf2f(unsigned short h) {
    return __uint_as_float(((unsigned)h) << 16);
}

// ---------------- KW0: init (deg, z) + one-time W prepack -------------------
// 196 blocks zero deg/z; blocks 0-3 additionally pack W1r|W1l into bf16
// hi/lo MFMA-fragment order pk[ks][quad][o][j] so k3's B-frag loads are
// coalesced dwordx4 runs. Element (o,ks,quad,j) = W_cat[o][ks*32+quad*8+j]
// (k<64: W1r, else W1l) -- identical values to on-the-fly conversion.
__global__ void kW0_init_pack(const float* __restrict__ W1l, const float* __restrict__ W1r,
                              short* __restrict__ pkhi, short* __restrict__ pklo,
                              int* __restrict__ deg, float* __restrict__ z) {
    int i = blockIdx.x * 256 + threadIdx.x;
    if (i < N_NODESC) deg[i] = 0;
    if (i < 256) z[i] = 0.0f;
    if (blockIdx.x < 4) {
        int ks = blockIdx.x;            // 0..3
        int t  = threadIdx.x;           // 256
        int o  = t & 127;
        int h  = t >> 7;                // quads {2h, 2h+1}
        const float* src = (ks < 2) ? (W1r + o * 64 + ks * 32)
                                    : (W1l + o * 64 + (ks - 2) * 32);
        #pragma unroll
        for (int qi = 0; qi < 2; qi++) {
            int q = 2 * h + qi;
            float4 a = *(const float4*)(src + q * 8);
            float4 b = *(const float4*)(src + q * 8 + 4);
            float v[8] = {a.x, a.y, a.z, a.w, b.x, b.y, b.z, b.w};
            bf16x8 hv, lv;
            #pragma unroll
            for (int j = 0; j < 8; j++) {
                unsigned short hh = f2bf(v[j]);
                hv[j] = (short)hh;
                lv[j] = (short)f2bf(v[j] - bf2f(hh));
            }
            int idx = ((ks * 4 + q) * 128 + o) * 8;
            *(bf16x8*)&pkhi[idx] = hv;
            *(bf16x8*)&pklo[idx] = lv;
        }
    }
}

// ---------------- K1: XCD-partitioned padded-bucket CSR build ---------------
// 4 dst-range groups; each group's bucket slice (3.2 MB) fits one XCD L2.
#define K1_BLOCKS 2048
#define K1_EPB 1563   // ceil(800000 / 512)
__global__ void k1_bucket(const int* __restrict__ ei, int* __restrict__ deg,
                          int* __restrict__ bucket) {
    int g   = blockIdx.x & 3;
    int idx = blockIdx.x >> 2;
    int lo = g * (N_NODESC / 4), hi = lo + (N_NODESC / 4);
    int e0 = idx * K1_EPB;
    for (int i = threadIdx.x; i < K1_EPB; i += 256) {
        int e = e0 + i;
        if (e < N_EDGESC) {
            int dst = ei[N_EDGESC + e];
            int src = ei[e];
            if (dst >= lo && dst < hi) {
                int slot = atomicAdd(&deg[dst], 1);
                if (slot < MAXDEG) bucket[dst * MAXDEG + slot] = src;
            }
        }
    }
}

// ---------------- K3: fused gather-mean + 3-term bf16 MFMA + epilogue -------
// v7: 512-thread / 8-wave blocks, 32-node tile. Round-5 showed occupancy
// pinned at ~30% (9.6 waves/CU) regardless of grid size with 256-thread
// blocks; the latency-bound gather needs more resident waves. At 512
// threads/block the CU thread limit gives 4 blocks x 8 waves = 32 waves/CU.
// Per-wave gather halves to 4 nodes (2 pairs, same 2-chain interleave, same
// per-node FP order -> bit-identical). MFMA: HID=128 = 8 strips of 16, one
// strip per wave (B-frags halve to 32 VGPRs, acc = 2 x f32x4). Epilogue sums
// 8 per-wave partials (cross-output association changes ~1ulp; budget 2e-3).
// launch_bounds(512,4) caps VGPR at 128 >> ~60 live set (no round-4 spill).
// 16x16x32 layouts (m89/m120): A[m=lane&15][k=quad*8+j],
// B[k=quad*8+j][n=lane&15], D[m=quad*4+reg][n=lane&15].
#define K3S 144   // LDS row stride in bf16 elems (128 + 16 pad)
#define K3BLK 32  // nodes per block

__launch_bounds__(512, 4)
__global__ void k3_fused(const float* __restrict__ x,
                         const int* __restrict__ deg, const int* __restrict__ bucket,
                         const short* __restrict__ pkhi, const short* __restrict__ pklo,
                         const float* __restrict__ b1l,
                         const float* __restrict__ W2l, const float* __restrict__ W2r,
                         float* __restrict__ s_out, float* __restrict__ t_out) {
    __shared__ __align__(16) short sAhi[K3BLK * K3S];   // 9216 B
    __shared__ __align__(16) short sAlo[K3BLK * K3S];   // 9216 B
    __shared__ float sSp[8][K3BLK], sTp[8][K3BLK];      // 2048 B

    int tid = threadIdx.x;
    int lane = tid & 63;
    int wave = tid >> 6;   // 0..7
    int col = lane & 15;   // c4 for gather, n-col for MFMA
    int quad = lane >> 4;  // g for gather, k-quad for MFMA
    int node0 = blockIdx.x * K3BLK;

    // ---- stage x (cols 0..63): 512 threads x float4 ------------------------
    float4 sv;
    {
        int n = tid >> 4, kc = tid & 15;   // 32 rows x 16 float4-chunks
        int node = node0 + n;
        if (node < N_NODESC) {
            sv = *(const float4*)(x + node * 64 + kc * 4);
        } else {
            sv = make_float4(0.f, 0.f, 0.f, 0.f);
        }
    }
    {
        int n = tid >> 4, kc = tid & 15;
        float v[4] = {sv.x, sv.y, sv.z, sv.w};
        short4v hv, lv;
        #pragma unroll
        for (int j = 0; j < 4; j++) {
            unsigned short h = f2bf(v[j]);
            hv[j] = (short)h;
            lv[j] = (short)f2bf(v[j] - bf2f(h));
        }
        *(short4v*)&sAhi[n * K3S + kc * 4] = hv;
        *(short4v*)&sAlo[n * K3S + kc * 4] = lv;
    }

    // ---- gather-mean agg half (cols 64..127): 2 node-PAIRS per wave --------
    {
        int base = node0 + wave * 4;
        int dA = 0, bA = 0, dB = 0, bB = 0;
        if (base < N_NODESC)     { dA = deg[base];     bA = bucket[base * MAXDEG + lane]; }
        if (base + 1 < N_NODESC) { dB = deg[base + 1]; bB = bucket[(base + 1) * MAXDEG + lane]; }
        for (int np = 0; np < 2; np++) {
            // prefetch next pair's deg + bucket rows (overlaps current gathers)
            int nN = base + 2 * np + 2;
            int dA2 = 0, bA2 = 0, dB2 = 0, bB2 = 0;
            if (np < 1) {
                if (nN < N_NODESC)     { dA2 = deg[nN];     bA2 = bucket[nN * MAXDEG + lane]; }
                if (nN + 1 < N_NODESC) { dB2 = deg[nN + 1]; bB2 = bucket[(nN + 1) * MAXDEG + lane]; }
            }
            int cA = min(dA, MAXDEG);
            int cB = min(dB, MAXDEG);
            int kmax = max(cA, cB);
            float4 aA = make_float4(0.f, 0.f, 0.f, 0.f);
            float4 aB = make_float4(0.f, 0.f, 0.f, 0.f);
            for (int k = 0; k < kmax; k += 8) {
                int i0 = k + quad, i1 = k + 4 + quad;
                int a0 = __shfl(bA, i0);
                int a1 = __shfl(bA, i1);
                int b0 = __shfl(bB, i0);
                int b1 = __shfl(bB, i1);
                if (i0 < cA) {
                    float4 v = ((const float4*)(x + a0 * 64))[col];
                    aA.x += v.x; aA.y += v.y; aA.z += v.z; aA.w += v.w;
                }
                if (i1 < cA) {
                    float4 v = ((const float4*)(x + a1 * 64))[col];
                    aA.x += v.x; aA.y += v.y; aA.z += v.z; aA.w += v.w;
                }
                if (i0 < cB) {
                    float4 v = ((const float4*)(x + b0 * 64))[col];
                    aB.x += v.x; aB.y += v.y; aB.z += v.z; aB.w += v.w;
                }
                if (i1 < cB) {
                    float4 v = ((const float4*)(x + b1 * 64))[col];
                    aB.x += v.x; aB.y += v.y; aB.z += v.z; aB.w += v.w;
                }
            }
            #pragma unroll
            for (int m = 16; m <= 32; m <<= 1) {
                aA.x += __shfl_xor(aA.x, m);
                aA.y += __shfl_xor(aA.y, m);
                aA.z += __shfl_xor(aA.z, m);
                aA.w += __shfl_xor(aA.w, m);
                aB.x += __shfl_xor(aB.x, m);
                aB.y += __shfl_xor(aB.y, m);
                aB.z += __shfl_xor(aB.z, m);
                aB.w += __shfl_xor(aB.w, m);
            }
            if (quad == 0) {
                int nlocA = wave * 4 + 2 * np;
                float invA = 1.0f / (float)max(dA, 1);
                float invB = 1.0f / (float)max(dB, 1);
                float vA[4] = {aA.x * invA, aA.y * invA, aA.z * invA, aA.w * invA};
                float vB[4] = {aB.x * invB, aB.y * invB, aB.z * invB, aB.w * invB};
                short4v hvA, lvA, hvB, lvB;
                #pragma unroll
                for (int j = 0; j < 4; j++) {
                    unsigned short hA = f2bf(vA[j]);
                    hvA[j] = (short)hA;
                    lvA[j] = (short)f2bf(vA[j] - bf2f(hA));
                    unsigned short hB = f2bf(vB[j]);
                    hvB[j] = (short)hB;
                    lvB[j] = (short)f2bf(vB[j] - bf2f(hB));
                }
                *(short4v*)&sAhi[nlocA * K3S + 64 + col * 4] = hvA;
                *(short4v*)&sAlo[nlocA * K3S + 64 + col * 4] = lvA;
                *(short4v*)&sAhi[(nlocA + 1) * K3S + 64 + col * 4] = hvB;
                *(short4v*)&sAlo[(nlocA + 1) * K3S + 64 + col * 4] = lvB;
            }
            dA = dA2; bA = bA2; dB = dB2; bB = bB2;
        }
    }

    // ---- B fragments: one 16-out strip per wave (o = wave*16 + col) --------
    int o = wave * 16 + col;
    bf16x8 bhi[4], blo[4];
    float bias_r = b1l[o], w2l_r = W2l[o], w2r_r = W2r[o];
    #pragma unroll
    for (int ks = 0; ks < 4; ks++) {
        int idx = ((ks * 4 + quad) * 128 + o) * 8;
        bhi[ks] = *(const bf16x8*)&pkhi[idx];
        blo[ks] = *(const bf16x8*)&pklo[idx];
    }
    __syncthreads();

    // ---- main loop: 4 ksteps x 2 node-tiles x 3 terms ----------------------
    f32x4 acc[2];
    acc[0] = (f32x4)0.f;
    acc[1] = (f32x4)0.f;

    #pragma unroll
    for (int ks = 0; ks < 4; ks++) {
        #pragma unroll
        for (int nt = 0; nt < 2; nt++) {
            int off = (nt * 16 + col) * K3S + ks * 32 + quad * 8;
            bf16x8 ah = *(const bf16x8*)&sAhi[off];
            bf16x8 al = *(const bf16x8*)&sAlo[off];
            acc[nt] = __builtin_amdgcn_mfma_f32_16x16x32_bf16(ah, bhi[ks], acc[nt], 0, 0, 0);
            acc[nt] = __builtin_amdgcn_mfma_f32_16x16x32_bf16(al, bhi[ks], acc[nt], 0, 0, 0);
            acc[nt] = __builtin_amdgcn_mfma_f32_16x16x32_bf16(ah, blo[ks], acc[nt], 0, 0, 0);
        }
    }

    // ---- epilogue: bias+relu+dots; col-lane shfl reduce + per-wave partials -
    #pragma unroll
    for (int nt = 0; nt < 2; nt++) {
        float sp[4], tp[4];
        #pragma unroll
        for (int reg = 0; reg < 4; reg++) {
            float h = fmaxf(acc[nt][reg] + bias_r, 0.f);
            sp[reg] = h * w2l_r;
            tp[reg] = h * w2r_r;
        }
        #pragma unroll
        for (int reg = 0; reg < 4; reg++) {
            #pragma unroll
            for (int m = 1; m <= 8; m <<= 1) {
                sp[reg] += __shfl_xor(sp[reg], m);
                tp[reg] += __shfl_xor(tp[reg], m);
            }
        }
        if (col == 0) {
            int nn = nt * 16 + quad * 4;
            #pragma unroll
            for (int reg = 0; reg < 4; reg++) {
                sSp[wave][nn + reg] = sp[reg];
                sTp[wave][nn + reg] = tp[reg];
            }
        }
    }
    __syncthreads();
    if (tid < K3BLK) {
        int node = node0 + tid;
        if (node < N_NODESC) {
            float ssum = 0.f, tsum = 0.f;
            #pragma unroll
            for (int w = 0; w < 8; w++) { ssum += sSp[w][tid]; tsum += sTp[w][tid]; }
            s_out[node] = ssum;
            t_out[node] = tsum;
        }
    }
}

// ---------------- K4: layer-2 scalar aggregation + relu -> v ----------------
__global__ void k4_layer2(const float* __restrict__ s, const float* __restrict__ t,
                          const int* __restrict__ deg, const int* __restrict__ bucket,
                          const float* __restrict__ b2l, float* __restrict__ v) {
    int tid = threadIdx.x;
    int lane = tid & 15;
    int node = blockIdx.x * 16 + (tid >> 4);
    int d = deg[node];
    int c = min(d, MAXDEG);
    float sum = 0.f;
    for (int k = lane; k < c; k += 16) sum += s[bucket[node * MAXDEG + k]];
    sum += __shfl_xor(sum, 1);
    sum += __shfl_xor(sum, 2);
    sum += __shfl_xor(sum, 4);
    sum += __shfl_xor(sum, 8);
    if (lane == 0) {
        float h = sum / (float)max(d, 1) + b2l[0] + t[node];
        v[node] = fmaxf(h, 0.f);
    }
}

// ---------------- K5: z_partial = fc1_W @ v (bias deferred to K6) -----------
// (round-2's fused head regressed 10us -> 102us via per-block __threadfence()
//  forcing cross-XCD L2 ordering. Separate k6 launch is strictly cheaper.)
__global__ void k5_fc1(const float* __restrict__ fc1W, const float* __restrict__ v,
                       float* __restrict__ z) {
    int row = blockIdx.x >> 2;
    int part = blockIdx.x & 3;
    const float4* W4 = (const float4*)(fc1W + row * 50000 + part * 12500);
    const float4* v4 = (const float4*)(v + part * 12500);
    float sum = 0.f;
    for (int i = threadIdx.x; i < 3125; i += 256) {
        float4 w = W4[i], a = v4[i];
        sum += w.x * a.x + w.y * a.y + w.z * a.z + w.w * a.w;
    }
    #pragma unroll
    for (int m = 1; m < 64; m <<= 1) sum += __shfl_xor(sum, m);
    __shared__ float red[4];
    if ((threadIdx.x & 63) == 0) red[threadIdx.x >> 6] = sum;
    __syncthreads();
    if (threadIdx.x == 0) atomicAdd(&z[row], red[0] + red[1] + red[2] + red[3]);
}

// ---------------- K6: pred = fc2_W @ (z + fc1_b) + fc2_b --------------------
__global__ void k6_head(const float* __restrict__ z, const float* __restrict__ fc1b,
                        const float* __restrict__ fc2W, const float* __restrict__ fc2b,
                        float* __restrict__ out) {
    int t = threadIdx.x;  // 256 threads
    float val = (z[t] + fc1b[t]) * fc2W[t];
    #pragma unroll
    for (int m = 1; m < 64; m <<= 1) val += __shfl_xor(val, m);
    __shared__ float red[4];
    if ((t & 63) == 0) red[t >> 6] = val;
    __syncthreads();
    if (t == 0) out[0] = red[0] + red[1] + red[2] + red[3] + fc2b[0];
}

extern "C" void kernel_launch(void* const* d_in, const int* in_sizes, int n_in,
                              void* d_out, int out_size, void* d_ws, size_t ws_size,
                              hipStream_t stream) {
    const float* x    = (const float*)d_in[0];
    const int*   ei   = (const int*)d_in[1];   // jax x64 disabled -> int32
    const float* W1l  = (const float*)d_in[2];
    const float* b1l  = (const float*)d_in[3];
    const float* W1r  = (const float*)d_in[4];
    const float* W2l  = (const float*)d_in[5];
    const float* b2l  = (const float*)d_in[6];
    const float* W2r  = (const float*)d_in[7];
    const float* fc1W = (const float*)d_in[8];
    const float* fc1b = (const float*)d_in[9];
    const float* fc2W = (const float*)d_in[10];
    const float* fc2b = (const float*)d_in[11];
    float* out = (float*)d_out;

    // workspace layout (bytes, 512-aligned)
    char* ws = (char*)d_ws;
    int*   deg    = (int*)  (ws + 0);          //   200,000 B
    float* z      = (float*)(ws + 200192);     //     1,024 B
    int*   bucket = (int*)  (ws + 201216);     // 12,800,000 B
    float* s      = (float*)(ws + 13001216);   //   200,000 B
    float* t      = (float*)(ws + 13201216);   //   200,000 B
    float* v      = (float*)(ws + 13401216);   //   200,000 B
    short* pkhi   = (short*)(ws + 13601280);   //    32,768 B (prepacked W hi)
    short* pklo   = (short*)(ws + 13634048);   //    32,768 B (prepacked W lo)
                                               // end 13,666,816

    kW0_init_pack<<<196,  256, 0, stream>>>(W1l, W1r, pkhi, pklo, deg, z);
    k1_bucket    <<<K1_BLOCKS, 256, 0, stream>>>(ei, deg, bucket);
    k3_fused     <<<1563, 512, 0, stream>>>(x, deg, bucket, pkhi, pklo, b1l, W2l, W2r, s, t);
    k4_layer2    <<<3125, 256, 0, stream>>>(s, t, deg, bucket, b2l, v);
    k5_fc1       <<<1024, 256, 0, stream>>>(fc1W, v, z);
    k6_head      <<<1,    256, 0, stream>>>(z, fc1b, fc2W, fc2b, out);
}